// Round 4
// baseline (464.340 us; speedup 1.0000x reference)
//
#include <hip/hip_runtime.h>
#include <hip/hip_fp16.h>
#include <math.h>

#define HIDDEN 1024
#define CODE_LEN 10
#define NUM_TABLE 32
#define RPB 8            // rows per block (K1)
#define BSTR 36          // padded words per 32-elem block in LDS
#define RSTR (32*BSTR)   // 1152 words per row
#define TBL_ELEMS (32u*1024u*1024u)   // 33,554,432

typedef float f32x4 __attribute__((ext_vector_type(4)));

__device__ __forceinline__ float4 f4(float a, float b, float c, float d) {
    return make_float4(a, b, c, d);
}

// Packed-friendly component-wise float2 ops. contract(off) marks each
// fmul/fadd non-fusable -> bit-identical to __fmul_rn/__fadd_rn, while
// leaving SLP free to merge the two lanes into v_pk_{mul,add}_f32.
__device__ __forceinline__ float2 f2mul(float2 a, float2 b) {
#pragma clang fp contract(off)
    float2 r; r.x = a.x * b.x; r.y = a.y * b.y; return r;
}
__device__ __forceinline__ float2 f2add(float2 a, float2 b) {
#pragma clang fp contract(off)
    float2 r; r.x = a.x + b.x; r.y = a.y + b.y; return r;
}
__device__ __forceinline__ float2 f2sub(float2 a, float2 b) {
#pragma clang fp contract(off)
    float2 r; r.x = a.x - b.x; r.y = a.y - b.y; return r;
}

// ============================================================================
// K1: cast tables fp32->fp16 + bit-exact LN/BH4/codes -> SC/CD in ws.
// Cast staggered 4 ways (start / after stage 0 / after stage 2 / after F).
// fp32 table + X loads are NON-TEMPORAL: the dead fp32 stream must not evict
// TBL16 from the LLC (the gather kernel re-reads TBL16 8x on average).
// Einsum + FWHT4 use packed float2 math (bit-identical op order, no fusion).
// CAST=false variant used by the monolithic fallback path.
// ============================================================================
template <bool SPLIT>
__global__ __launch_bounds__(256, 4) void compute_kernel(
    const float* __restrict__ X,   // [rows,1024]
    const float* __restrict__ G,   // [1024] ln_gamma
    const float* __restrict__ Bt,  // [1024] ln_beta
    const float* __restrict__ W,   // [1,4,32,32,32] bh4_weight
    const float* __restrict__ ZB,  // [320] bh4_bias
    const float* __restrict__ TBL, // [32*1024,1024] tables flat (fp32)
    const float* __restrict__ OB,  // [1024] out_bias
    float* __restrict__ OUT,       // [rows,1024]
    __half* __restrict__ TBL16,    // ws: fp16 tables
    float* __restrict__ SC,        // ws: [rows*32] scores
    int*   __restrict__ CD)        // ws: [rows*32] codes
{
    __shared__ float lds[RPB * RSTR];          // 36864 B
    __shared__ float l_sc[RPB * NUM_TABLE];    // only used by !SPLIT path
    __shared__ int   l_cd[RPB * NUM_TABLE];

    const int t    = threadIdx.x;
    const int lane = t & 63;
    const int wv   = t >> 6;
    const int row0 = blockIdx.x * RPB;

    auto do_cast = [&]() {
        const f32x4* src = reinterpret_cast<const f32x4*>(TBL + (size_t)blockIdx.x * 32768);
        __half*      dst = TBL16 + (size_t)blockIdx.x * 32768;
#pragma unroll
        for (int k = 0; k < 16; k++) {
            const int i4 = (k*256 + t) * 2;            // in f32x4 units
            const f32x4 a = __builtin_nontemporal_load(src + i4);
            const f32x4 b = __builtin_nontemporal_load(src + i4 + 1);
            union { uint4 u4; __half2 h2[4]; } pk;
            pk.h2[0] = __floats2half2_rn(a.x, a.y);
            pk.h2[1] = __floats2half2_rn(a.z, a.w);
            pk.h2[2] = __floats2half2_rn(b.x, b.y);
            pk.h2[3] = __floats2half2_rn(b.z, b.w);
            *reinterpret_cast<uint4*>(dst + (k*256 + t)*8) = pk.u4;
        }
    };

    // ---------- Phase 0 (SPLIT, parity-0 blocks): cast slice ----------
    if constexpr (SPLIT) {
        if ((blockIdx.x & 3) == 0) do_cast();
    }

    // ---------- Phase A: load raw x into padded LDS (non-temporal: read once) ----------
#pragma unroll
    for (int u = 0; u < 2; u++) {
        const int r = wv + 4*u;
        const f32x4* xr = reinterpret_cast<const f32x4*>(X + (size_t)(row0 + r) * HIDDEN);
#pragma unroll
        for (int q = 0; q < 4; q++) {
            const int p = q*256 + 4*lane;
            const f32x4 v = __builtin_nontemporal_load(xr + (p >> 2));
            *reinterpret_cast<f32x4*>(lds + r*RSTR + (p >> 5)*BSTR + (p & 31)) = v;
        }
    }

    // ---------- Phase B: numpy-pairwise mean/var (bit-exact np.mean order) ----------
    float mu0, mu4, rs0, rs4;
    {
        float bsum = 0.f;
        if (lane < 16) {
            const int row = wv + 4*(lane >> 3);
            const int blk = lane & 7;
            const float* bp = lds + row*RSTR + blk*4*BSTR;
            float r8[8];
            {
                const float4 f0 = *reinterpret_cast<const float4*>(bp);
                const float4 f1 = *reinterpret_cast<const float4*>(bp + 4);
                r8[0]=f0.x; r8[1]=f0.y; r8[2]=f0.z; r8[3]=f0.w;
                r8[4]=f1.x; r8[5]=f1.y; r8[6]=f1.z; r8[7]=f1.w;
            }
#pragma unroll
            for (int m = 1; m < 16; m++) {
                const int p = 8*m;
                const float* qp = bp + (p >> 5)*BSTR + (p & 31);
                const float4 f0 = *reinterpret_cast<const float4*>(qp);
                const float4 f1 = *reinterpret_cast<const float4*>(qp + 4);
                r8[0]=__fadd_rn(r8[0],f0.x); r8[1]=__fadd_rn(r8[1],f0.y);
                r8[2]=__fadd_rn(r8[2],f0.z); r8[3]=__fadd_rn(r8[3],f0.w);
                r8[4]=__fadd_rn(r8[4],f1.x); r8[5]=__fadd_rn(r8[5],f1.y);
                r8[6]=__fadd_rn(r8[6],f1.z); r8[7]=__fadd_rn(r8[7],f1.w);
            }
            bsum = __fadd_rn(__fadd_rn(__fadd_rn(r8[0],r8[1]), __fadd_rn(r8[2],r8[3])),
                             __fadd_rn(__fadd_rn(r8[4],r8[5]), __fadd_rn(r8[6],r8[7])));
        }
        float v = bsum;
        v = __fadd_rn(v, __shfl_xor(v, 1, 64));
        v = __fadd_rn(v, __shfl_xor(v, 2, 64));
        v = __fadd_rn(v, __shfl_xor(v, 4, 64));
        mu0 = __fmul_rn(__shfl(v, 0, 64), 0.0009765625f);
        mu4 = __fmul_rn(__shfl(v, 8, 64), 0.0009765625f);

        float bss = 0.f;
        if (lane < 16) {
            const int row = wv + 4*(lane >> 3);
            const float mu = (lane & 8) ? mu4 : mu0;
            const int blk = lane & 7;
            const float* bp = lds + row*RSTR + blk*4*BSTR;
            float r8[8];
            {
                const float4 f0 = *reinterpret_cast<const float4*>(bp);
                const float4 f1 = *reinterpret_cast<const float4*>(bp + 4);
                float d;
                d=__fsub_rn(f0.x,mu); r8[0]=__fmul_rn(d,d);
                d=__fsub_rn(f0.y,mu); r8[1]=__fmul_rn(d,d);
                d=__fsub_rn(f0.z,mu); r8[2]=__fmul_rn(d,d);
                d=__fsub_rn(f0.w,mu); r8[3]=__fmul_rn(d,d);
                d=__fsub_rn(f1.x,mu); r8[4]=__fmul_rn(d,d);
                d=__fsub_rn(f1.y,mu); r8[5]=__fmul_rn(d,d);
                d=__fsub_rn(f1.z,mu); r8[6]=__fmul_rn(d,d);
                d=__fsub_rn(f1.w,mu); r8[7]=__fmul_rn(d,d);
            }
#pragma unroll
            for (int m = 1; m < 16; m++) {
                const int p = 8*m;
                const float* qp = bp + (p >> 5)*BSTR + (p & 31);
                const float4 f0 = *reinterpret_cast<const float4*>(qp);
                const float4 f1 = *reinterpret_cast<const float4*>(qp + 4);
                float d;
                d=__fsub_rn(f0.x,mu); r8[0]=__fadd_rn(r8[0],__fmul_rn(d,d));
                d=__fsub_rn(f0.y,mu); r8[1]=__fadd_rn(r8[1],__fmul_rn(d,d));
                d=__fsub_rn(f0.z,mu); r8[2]=__fadd_rn(r8[2],__fmul_rn(d,d));
                d=__fsub_rn(f0.w,mu); r8[3]=__fadd_rn(r8[3],__fmul_rn(d,d));
                d=__fsub_rn(f1.x,mu); r8[4]=__fadd_rn(r8[4],__fmul_rn(d,d));
                d=__fsub_rn(f1.y,mu); r8[5]=__fadd_rn(r8[5],__fmul_rn(d,d));
                d=__fsub_rn(f1.z,mu); r8[6]=__fadd_rn(r8[6],__fmul_rn(d,d));
                d=__fsub_rn(f1.w,mu); r8[7]=__fadd_rn(r8[7],__fmul_rn(d,d));
            }
            bss = __fadd_rn(__fadd_rn(__fadd_rn(r8[0],r8[1]), __fadd_rn(r8[2],r8[3])),
                            __fadd_rn(__fadd_rn(r8[4],r8[5]), __fadd_rn(r8[6],r8[7])));
        }
        float v2 = bss;
        v2 = __fadd_rn(v2, __shfl_xor(v2, 1, 64));
        v2 = __fadd_rn(v2, __shfl_xor(v2, 2, 64));
        v2 = __fadd_rn(v2, __shfl_xor(v2, 4, 64));
        const float var0 = __fmul_rn(__shfl(v2, 0, 64), 0.0009765625f);
        const float var4 = __fmul_rn(__shfl(v2, 8, 64), 0.0009765625f);
        rs0 = __fdiv_rn(1.0f, __fsqrt_rn(__fadd_rn(var0, 1e-12f)));
        rs4 = __fdiv_rn(1.0f, __fsqrt_rn(__fadd_rn(var4, 1e-12f)));
    }

    // ---------- Phase C: xn = ((x-mu)*rstd)*gamma + beta, in place ----------
    float4 xn0[2], xn1[2];
    {
        float4 g4[4], b4[4];
#pragma unroll
        for (int q = 0; q < 4; q++) {
            g4[q] = *reinterpret_cast<const float4*>(G  + q*256 + 4*lane);
            b4[q] = *reinterpret_cast<const float4*>(Bt + q*256 + 4*lane);
        }
#pragma unroll
        for (int u = 0; u < 2; u++) {
            const int r = wv + 4*u;
            const float mu = u ? mu4 : mu0;
            const float rstd = u ? rs4 : rs0;
#pragma unroll
            for (int q = 0; q < 4; q++) {
                const int p = q*256 + 4*lane;
                float* ptr = lds + r*RSTR + (p >> 5)*BSTR + (p & 31);
                const float4 x4 = *reinterpret_cast<float4*>(ptr);
                float4 xn;
                xn.x = __fadd_rn(__fmul_rn(__fmul_rn(__fsub_rn(x4.x, mu), rstd), g4[q].x), b4[q].x);
                xn.y = __fadd_rn(__fmul_rn(__fmul_rn(__fsub_rn(x4.y, mu), rstd), g4[q].y), b4[q].y);
                xn.z = __fadd_rn(__fmul_rn(__fmul_rn(__fsub_rn(x4.z, mu), rstd), g4[q].z), b4[q].z);
                xn.w = __fadd_rn(__fmul_rn(__fmul_rn(__fsub_rn(x4.w, mu), rstd), g4[q].w), b4[q].w);
                *reinterpret_cast<float4*>(ptr) = xn;
                if (q == 0) xn0[u] = xn;
                if (q == 1) xn1[u] = xn;
            }
        }
    }
    __syncthreads();

    // ---------- Phase D: 4 BH4 stages, np-einsum order + ascending FWHT ----------
    // Einsum packed as float2 pairs over the output dim (c0,c1)/(c2,c3):
    // per-accumulator-component order is IDENTICAL to the scalar version
    // (h.x*w0.c, then h.y*w1.c, h.z*w2.c, h.w*w3.c).
    const int Bm = t >> 3;
    const int j0 = (t & 7) * 4;
#pragma unroll 1
    for (int s = 0; s < 4; s++) {
        float2 acc2[RPB][2];
#pragma unroll
        for (int r = 0; r < RPB; r++) {
            acc2[r][0] = make_float2(0.f, 0.f);
            acc2[r][1] = make_float2(0.f, 0.f);
        }
        const float* Wb = W + s*32768 + Bm*1024 + j0;
#pragma unroll 2
        for (int iq = 0; iq < 8; iq++) {
            const float4 w0 = *reinterpret_cast<const float4*>(Wb + (iq*4 + 0)*32);
            const float4 w1 = *reinterpret_cast<const float4*>(Wb + (iq*4 + 1)*32);
            const float4 w2 = *reinterpret_cast<const float4*>(Wb + (iq*4 + 2)*32);
            const float4 w3 = *reinterpret_cast<const float4*>(Wb + (iq*4 + 3)*32);
#pragma unroll
            for (int r = 0; r < RPB; r++) {
                const float4 h4 = *reinterpret_cast<const float4*>(lds + r*RSTR + Bm*BSTR + iq*4);
                const float2 hx = make_float2(h4.x, h4.x);
                const float2 hy = make_float2(h4.y, h4.y);
                const float2 hz = make_float2(h4.z, h4.z);
                const float2 hw = make_float2(h4.w, h4.w);
                acc2[r][0] = f2add(acc2[r][0], f2mul(hx, make_float2(w0.x, w0.y)));
                acc2[r][1] = f2add(acc2[r][1], f2mul(hx, make_float2(w0.z, w0.w)));
                acc2[r][0] = f2add(acc2[r][0], f2mul(hy, make_float2(w1.x, w1.y)));
                acc2[r][1] = f2add(acc2[r][1], f2mul(hy, make_float2(w1.z, w1.w)));
                acc2[r][0] = f2add(acc2[r][0], f2mul(hz, make_float2(w2.x, w2.y)));
                acc2[r][1] = f2add(acc2[r][1], f2mul(hz, make_float2(w2.z, w2.w)));
                acc2[r][0] = f2add(acc2[r][0], f2mul(hw, make_float2(w3.x, w3.y)));
                acc2[r][1] = f2add(acc2[r][1], f2mul(hw, make_float2(w3.z, w3.w)));
            }
        }
        // No barrier here: writers below == readers above (group Bm, same wave).
#pragma unroll
        for (int r = 0; r < RPB; r++) {
            const float a = acc2[r][0].x, b = acc2[r][0].y;
            const float c = acc2[r][1].x, d = acc2[r][1].y;
            const float s0 = __fadd_rn(a,b), d0 = __fsub_rn(a,b);
            const float s1 = __fadd_rn(c,d), d1 = __fsub_rn(c,d);
            *reinterpret_cast<float4*>(lds + r*RSTR + Bm*BSTR + j0) =
                f4(__fadd_rn(s0,s1), __fadd_rn(d0,d1), __fsub_rn(s0,s1), __fsub_rn(d0,d1));
        }
        __syncthreads();

        {   // FWHT over 8 float4 groups — packed as float2 halves (same ops)
            const int rr = t >> 5, bb = t & 31;
            float* bp = lds + rr*RSTR + bb*BSTR;
            float2 vl[8], vh[8];
#pragma unroll
            for (int k = 0; k < 8; k++) {
                const float4 tv = *reinterpret_cast<float4*>(bp + 4*k);
                vl[k] = make_float2(tv.x, tv.y);
                vh[k] = make_float2(tv.z, tv.w);
            }
#pragma unroll
            for (int m = 1; m < 8; m <<= 1) {
#pragma unroll
                for (int k = 0; k < 8; k++) if (!(k & m)) {
                    const float2 al = vl[k], bl = vl[k | m];
                    const float2 ah = vh[k], bh = vh[k | m];
                    vl[k] = f2add(al, bl); vl[k | m] = f2sub(al, bl);
                    vh[k] = f2add(ah, bh); vh[k | m] = f2sub(ah, bh);
                }
            }
#pragma unroll
            for (int k = 0; k < 8; k++)
                *reinterpret_cast<float4*>(bp + 4*k) = f4(vl[k].x, vl[k].y, vh[k].x, vh[k].y);
        }
        __syncthreads();

        {
            const int rr = t >> 5, J = t & 31;
            float* bp = lds + rr*RSTR + J;
            float g[32];
#pragma unroll
            for (int k = 0; k < 32; k++) g[k] = bp[k*BSTR];
#pragma unroll
            for (int m = 1; m < 32; m <<= 1) {
#pragma unroll
                for (int k = 0; k < 32; k++) if (!(k & m)) {
                    const float a = g[k], b = g[k | m];
                    g[k] = __fadd_rn(a,b); g[k | m] = __fsub_rn(a,b);
                }
            }
#pragma unroll
            for (int k = 0; k < 32; k++) bp[k*BSTR] = g[k];
        }
        __syncthreads();

        // ---- 4-way cast stagger: parity 1 after stage 0, parity 2 after stage 2 ----
        if constexpr (SPLIT) {
            if ((blockIdx.x & 3) == 1 && s == 0) do_cast();
            if ((blockIdx.x & 3) == 2 && s == 2) do_cast();
        }
    }

    // ---------- Phase E: z = (0.7*h) + (0.3*xn) + bias, p < 320 ----------
    {
        const float c0 = 0.7f, c1 = 0.3f;
#pragma unroll
        for (int u = 0; u < 2; u++) {
            const int r = wv + 4*u;
            {
                const int p = 4*lane;
                const float4 zb = *reinterpret_cast<const float4*>(ZB + p);
                float* zp = lds + r*RSTR + (p >> 5)*BSTR + (p & 31);
                float4 h4 = *reinterpret_cast<float4*>(zp);
                h4.x = __fadd_rn(__fadd_rn(__fmul_rn(c0,h4.x), __fmul_rn(c1,xn0[u].x)), zb.x);
                h4.y = __fadd_rn(__fadd_rn(__fmul_rn(c0,h4.y), __fmul_rn(c1,xn0[u].y)), zb.y);
                h4.z = __fadd_rn(__fadd_rn(__fmul_rn(c0,h4.z), __fmul_rn(c1,xn0[u].z)), zb.z);
                h4.w = __fadd_rn(__fadd_rn(__fmul_rn(c0,h4.w), __fmul_rn(c1,xn0[u].w)), zb.w);
                *reinterpret_cast<float4*>(zp) = h4;
            }
            if (lane < 16) {
                const int p = 256 + 4*lane;
                const float4 zb = *reinterpret_cast<const float4*>(ZB + p);
                float* zp = lds + r*RSTR + (p >> 5)*BSTR + (p & 31);
                float4 h4 = *reinterpret_cast<float4*>(zp);
                h4.x = __fadd_rn(__fadd_rn(__fmul_rn(c0,h4.x), __fmul_rn(c1,xn1[u].x)), zb.x);
                h4.y = __fadd_rn(__fadd_rn(__fmul_rn(c0,h4.y), __fmul_rn(c1,xn1[u].y)), zb.y);
                h4.z = __fadd_rn(__fadd_rn(__fmul_rn(c0,h4.z), __fmul_rn(c1,xn1[u].z)), zb.z);
                h4.w = __fadd_rn(__fadd_rn(__fmul_rn(c0,h4.w), __fmul_rn(c1,xn1[u].w)), zb.w);
                *reinterpret_cast<float4*>(zp) = h4;
            }
        }
    }
    __syncthreads();

    // ---------- Phase F: codes & scores ----------
    {
        const int r = t >> 5, T = t & 31;
        int code = 0; float sc = 1.f;
#pragma unroll
        for (int d = 0; d < CODE_LEN; d++) {
            const int p = T*CODE_LEN + d;
            const float z = lds[r*RSTR + (p >> 5)*BSTR + (p & 31)];
            if (z > 0.f) code |= (1 << d);
            sc *= 1.f / (1.f + expf(-fabsf(z)));
        }
        if constexpr (SPLIT) {
            SC[(size_t)row0 * NUM_TABLE + t] = sc;
            CD[(size_t)row0 * NUM_TABLE + t] = code;
        } else {
            l_sc[t] = sc;
            l_cd[t] = code;
        }
    }

    // ---------- parity-3 blocks: cast slice last ----------
    if constexpr (SPLIT) {
        if ((blockIdx.x & 3) == 3) do_cast();
    }

    // ---------- Fallback-only: fp32 gather in-kernel (proven R3 path) ----------
    if constexpr (!SPLIT) {
        __syncthreads();
        float4 ob[4];
#pragma unroll
        for (int q = 0; q < 4; q++)
            ob[q] = *reinterpret_cast<const float4*>(OB + q*256 + 4*lane);
#pragma unroll
        for (int u = 0; u < 2; u++) {
            const int r = wv + 4*u;
            float4 o[4];
#pragma unroll
            for (int q = 0; q < 4; q++) o[q] = ob[q];
#pragma unroll 4
            for (int T = 0; T < NUM_TABLE; T++) {
                const float sc  = l_sc[r*NUM_TABLE + T];
                const int code  = l_cd[r*NUM_TABLE + T];
                const float* tbf = TBL + ((size_t)(T*1024 + code)) * 1024;
#pragma unroll
                for (int q = 0; q < 4; q++) {
                    const float4 tv = *reinterpret_cast<const float4*>(tbf + q*256 + 4*lane);
                    o[q].x += sc * tv.x; o[q].y += sc * tv.y;
                    o[q].z += sc * tv.z; o[q].w += sc * tv.w;
                }
            }
            float* orow = OUT + (size_t)(row0 + r) * HIDDEN;
#pragma unroll
            for (int q = 0; q < 4; q++)
                *reinterpret_cast<float4*>(orow + q*256 + 4*lane) = o[q];
        }
    }
}

// ============================================================================
// K2: fp16 gather. One wave per row; lane owns halves [lane*8..+7] and
// [512+lane*8..+7]. 8-table groups; sched_barrier(0) pins the issue/consume
// split (16 loads genuinely outstanding). OUT stores non-temporal (keep LLC
// for TBL16 reuse).
// ============================================================================
__global__ __launch_bounds__(256, 4) void gather_kernel(
    const __half* __restrict__ TBL16,
    const float* __restrict__ SC,
    const int*   __restrict__ CD,
    const float* __restrict__ OB,
    float* __restrict__ OUT)
{
    __shared__ float s_sc[4 * NUM_TABLE];
    __shared__ int   s_cd[4 * NUM_TABLE];
    const int t = threadIdx.x, lane = t & 63, wv = t >> 6;
    const int row0 = blockIdx.x * 4;

    if (t < 128) {
        s_sc[t] = SC[(size_t)row0 * NUM_TABLE + t];
        s_cd[t] = CD[(size_t)row0 * NUM_TABLE + t];
    }
    __syncthreads();

    f32x4 o[4];
    o[0] = *reinterpret_cast<const f32x4*>(OB + lane*8);
    o[1] = *reinterpret_cast<const f32x4*>(OB + lane*8 + 4);
    o[2] = *reinterpret_cast<const f32x4*>(OB + 512 + lane*8);
    o[3] = *reinterpret_cast<const f32x4*>(OB + 512 + lane*8 + 4);

#pragma unroll 1
    for (int Tg = 0; Tg < NUM_TABLE; Tg += 8) {
        uint4 va[16];
        float sc[8];
        // ---- issue phase: 16 loads in flight ----
#pragma unroll
        for (int k = 0; k < 8; k++) {
            const int T = Tg + k;
            sc[k] = s_sc[wv*NUM_TABLE + T];
            const int code = s_cd[wv*NUM_TABLE + T];
            const __half* tb = TBL16 + (((size_t)(T*1024 + code)) << 10);
            va[2*k]   = *reinterpret_cast<const uint4*>(tb + lane*8);
            va[2*k+1] = *reinterpret_cast<const uint4*>(tb + 512 + lane*8);
        }
        // pin the split: no load may sink below, no consume may hoist above
        __builtin_amdgcn_sched_barrier(0);
        // ---- consume phase ----
#pragma unroll
        for (int k = 0; k < 8; k++) {
            const __half2* h0 = reinterpret_cast<const __half2*>(&va[2*k]);
            const __half2* h1 = reinterpret_cast<const __half2*>(&va[2*k+1]);
            const float s = sc[k];
            float2 f;
            f = __half22float2(h0[0]); o[0].x += s*f.x; o[0].y += s*f.y;
            f = __half22float2(h0[1]); o[0].z += s*f.x; o[0].w += s*f.y;
            f = __half22float2(h0[2]); o[1].x += s*f.x; o[1].y += s*f.y;
            f = __half22float2(h0[3]); o[1].z += s*f.x; o[1].w += s*f.y;
            f = __half22float2(h1[0]); o[2].x += s*f.x; o[2].y += s*f.y;
            f = __half22float2(h1[1]); o[2].z += s*f.x; o[2].w += s*f.y;
            f = __half22float2(h1[2]); o[3].x += s*f.x; o[3].y += s*f.y;
            f = __half22float2(h1[3]); o[3].z += s*f.x; o[3].w += s*f.y;
        }
    }

    float* orow = OUT + (size_t)(row0 + wv) * HIDDEN;
    __builtin_nontemporal_store(o[0], reinterpret_cast<f32x4*>(orow + lane*8));
    __builtin_nontemporal_store(o[1], reinterpret_cast<f32x4*>(orow + lane*8 + 4));
    __builtin_nontemporal_store(o[2], reinterpret_cast<f32x4*>(orow + 512 + lane*8));
    __builtin_nontemporal_store(o[3], reinterpret_cast<f32x4*>(orow + 512 + lane*8 + 4));
}

extern "C" void kernel_launch(void* const* d_in, const int* in_sizes, int n_in,
                              void* d_out, int out_size, void* d_ws, size_t ws_size,
                              hipStream_t stream) {
    const float* X   = (const float*)d_in[0];
    const float* G   = (const float*)d_in[1];
    const float* Bt  = (const float*)d_in[2];
    const float* W   = (const float*)d_in[3];
    const float* ZB  = (const float*)d_in[4];
    const float* TBL = (const float*)d_in[5];
    const float* OB  = (const float*)d_in[6];
    float* OUT = (float*)d_out;

    const int rows = in_sizes[0] / HIDDEN;     // 8192
    const int grid = rows / RPB;               // 1024 blocks

    // ws layout: [tables fp16: 64 MiB][scores: rows*32 f32][codes: rows*32 i32]
    const size_t tbl_bytes = (size_t)TBL_ELEMS * sizeof(__half);
    const size_t sc_bytes  = (size_t)rows * NUM_TABLE * sizeof(float);
    const size_t need = tbl_bytes + 2 * sc_bytes;
    __half* TBL16 = (__half*)d_ws;
    float*  SC    = (float*)((char*)d_ws + tbl_bytes);
    int*    CD    = (int*)((char*)d_ws + tbl_bytes + sc_bytes);

    if (ws_size >= need && grid == 1024) {
        hipLaunchKernelGGL(compute_kernel<true>, dim3(grid), dim3(256), 0, stream,
                           X, G, Bt, W, ZB, TBL, OB, OUT, TBL16, SC, CD);
        hipLaunchKernelGGL(gather_kernel, dim3(rows / 4), dim3(256), 0, stream,
                           TBL16, SC, CD, OB, OUT);
    } else {
        // proven R3 monolithic fp32 path
        hipLaunchKernelGGL(compute_kernel<false>, dim3(grid), dim3(256), 0, stream,
                           X, G, Bt, W, ZB, TBL, OB, OUT, TBL16, SC, CD);
    }
}

// Round 5
// 451.193 us; speedup vs baseline: 1.0291x; 1.0291x over previous
//
#include <hip/hip_runtime.h>
#include <hip/hip_fp16.h>
#include <math.h>

#define HIDDEN 1024
#define CODE_LEN 10
#define NUM_TABLE 32
#define RPB 8            // rows per block (K1)
#define BSTR 36          // padded words per 32-elem block in LDS
#define RSTR (32*BSTR)   // 1152 words per row
#define TBL_ELEMS (32u*1024u*1024u)   // 33,554,432

__device__ __forceinline__ float4 f4(float a, float b, float c, float d) {
    return make_float4(a, b, c, d);
}

// ============================================================================
// K1: cast tables fp32->fp16 + bit-exact LN/BH4/codes -> SC/CD in ws.
// EXACT round-3 structure (proven 121.8 us): 2-way block-parity cast stagger,
// scalar __fmul_rn/__fadd_rn einsum (R4's f2-packing + NT loads regressed),
// no barrier between einsum and its same-wave FWHT4 writeback.
// CAST=false variant used by the monolithic fallback path.
// ============================================================================
template <bool SPLIT>
__global__ __launch_bounds__(256, 4) void compute_kernel(
    const float* __restrict__ X,   // [rows,1024]
    const float* __restrict__ G,   // [1024] ln_gamma
    const float* __restrict__ Bt,  // [1024] ln_beta
    const float* __restrict__ W,   // [1,4,32,32,32] bh4_weight
    const float* __restrict__ ZB,  // [320] bh4_bias
    const float* __restrict__ TBL, // [32*1024,1024] tables flat (fp32)
    const float* __restrict__ OB,  // [1024] out_bias
    float* __restrict__ OUT,       // [rows,1024]
    __half* __restrict__ TBL16,    // ws: fp16 tables
    float* __restrict__ SC,        // ws: [rows*32] scores
    int*   __restrict__ CD)        // ws: [rows*32] codes
{
    __shared__ float lds[RPB * RSTR];          // 36864 B
    __shared__ float l_sc[RPB * NUM_TABLE];    // only used by !SPLIT path
    __shared__ int   l_cd[RPB * NUM_TABLE];

    const int t    = threadIdx.x;
    const int lane = t & 63;
    const int wv   = t >> 6;
    const int row0 = blockIdx.x * RPB;

    auto do_cast = [&]() {
        const float* src = TBL   + (size_t)blockIdx.x * 32768;
        __half*      dst = TBL16 + (size_t)blockIdx.x * 32768;
#pragma unroll
        for (int k = 0; k < 16; k++) {
            const int idx = (k*256 + t) * 8;
            const float4 a = *reinterpret_cast<const float4*>(src + idx);
            const float4 b = *reinterpret_cast<const float4*>(src + idx + 4);
            union { uint4 u4; __half2 h2[4]; } pk;
            pk.h2[0] = __floats2half2_rn(a.x, a.y);
            pk.h2[1] = __floats2half2_rn(a.z, a.w);
            pk.h2[2] = __floats2half2_rn(b.x, b.y);
            pk.h2[3] = __floats2half2_rn(b.z, b.w);
            *reinterpret_cast<uint4*>(dst + idx) = pk.u4;
        }
    };

    // ---------- Phase 0 (SPLIT, even blocks): cast table slice fp32->fp16 ----------
    if constexpr (SPLIT) {
        if ((blockIdx.x & 1) == 0) do_cast();
    }

    // ---------- Phase A: load raw x into padded LDS ----------
#pragma unroll
    for (int u = 0; u < 2; u++) {
        const int r = wv + 4*u;
        const float* xr = X + (size_t)(row0 + r) * HIDDEN;
#pragma unroll
        for (int q = 0; q < 4; q++) {
            const int p = q*256 + 4*lane;
            const float4 v = *reinterpret_cast<const float4*>(xr + p);
            *reinterpret_cast<float4*>(lds + r*RSTR + (p >> 5)*BSTR + (p & 31)) = v;
        }
    }

    // ---------- Phase B: numpy-pairwise mean/var (bit-exact np.mean order) ----------
    float mu0, mu4, rs0, rs4;
    {
        float bsum = 0.f;
        if (lane < 16) {
            const int row = wv + 4*(lane >> 3);
            const int blk = lane & 7;
            const float* bp = lds + row*RSTR + blk*4*BSTR;
            float r8[8];
            {
                const float4 f0 = *reinterpret_cast<const float4*>(bp);
                const float4 f1 = *reinterpret_cast<const float4*>(bp + 4);
                r8[0]=f0.x; r8[1]=f0.y; r8[2]=f0.z; r8[3]=f0.w;
                r8[4]=f1.x; r8[5]=f1.y; r8[6]=f1.z; r8[7]=f1.w;
            }
#pragma unroll
            for (int m = 1; m < 16; m++) {
                const int p = 8*m;
                const float* qp = bp + (p >> 5)*BSTR + (p & 31);
                const float4 f0 = *reinterpret_cast<const float4*>(qp);
                const float4 f1 = *reinterpret_cast<const float4*>(qp + 4);
                r8[0]=__fadd_rn(r8[0],f0.x); r8[1]=__fadd_rn(r8[1],f0.y);
                r8[2]=__fadd_rn(r8[2],f0.z); r8[3]=__fadd_rn(r8[3],f0.w);
                r8[4]=__fadd_rn(r8[4],f1.x); r8[5]=__fadd_rn(r8[5],f1.y);
                r8[6]=__fadd_rn(r8[6],f1.z); r8[7]=__fadd_rn(r8[7],f1.w);
            }
            bsum = __fadd_rn(__fadd_rn(__fadd_rn(r8[0],r8[1]), __fadd_rn(r8[2],r8[3])),
                             __fadd_rn(__fadd_rn(r8[4],r8[5]), __fadd_rn(r8[6],r8[7])));
        }
        float v = bsum;
        v = __fadd_rn(v, __shfl_xor(v, 1, 64));
        v = __fadd_rn(v, __shfl_xor(v, 2, 64));
        v = __fadd_rn(v, __shfl_xor(v, 4, 64));
        mu0 = __fmul_rn(__shfl(v, 0, 64), 0.0009765625f);
        mu4 = __fmul_rn(__shfl(v, 8, 64), 0.0009765625f);

        float bss = 0.f;
        if (lane < 16) {
            const int row = wv + 4*(lane >> 3);
            const float mu = (lane & 8) ? mu4 : mu0;
            const int blk = lane & 7;
            const float* bp = lds + row*RSTR + blk*4*BSTR;
            float r8[8];
            {
                const float4 f0 = *reinterpret_cast<const float4*>(bp);
                const float4 f1 = *reinterpret_cast<const float4*>(bp + 4);
                float d;
                d=__fsub_rn(f0.x,mu); r8[0]=__fmul_rn(d,d);
                d=__fsub_rn(f0.y,mu); r8[1]=__fmul_rn(d,d);
                d=__fsub_rn(f0.z,mu); r8[2]=__fmul_rn(d,d);
                d=__fsub_rn(f0.w,mu); r8[3]=__fmul_rn(d,d);
                d=__fsub_rn(f1.x,mu); r8[4]=__fmul_rn(d,d);
                d=__fsub_rn(f1.y,mu); r8[5]=__fmul_rn(d,d);
                d=__fsub_rn(f1.z,mu); r8[6]=__fmul_rn(d,d);
                d=__fsub_rn(f1.w,mu); r8[7]=__fmul_rn(d,d);
            }
#pragma unroll
            for (int m = 1; m < 16; m++) {
                const int p = 8*m;
                const float* qp = bp + (p >> 5)*BSTR + (p & 31);
                const float4 f0 = *reinterpret_cast<const float4*>(qp);
                const float4 f1 = *reinterpret_cast<const float4*>(qp + 4);
                float d;
                d=__fsub_rn(f0.x,mu); r8[0]=__fadd_rn(r8[0],__fmul_rn(d,d));
                d=__fsub_rn(f0.y,mu); r8[1]=__fadd_rn(r8[1],__fmul_rn(d,d));
                d=__fsub_rn(f0.z,mu); r8[2]=__fadd_rn(r8[2],__fmul_rn(d,d));
                d=__fsub_rn(f0.w,mu); r8[3]=__fadd_rn(r8[3],__fmul_rn(d,d));
                d=__fsub_rn(f1.x,mu); r8[4]=__fadd_rn(r8[4],__fmul_rn(d,d));
                d=__fsub_rn(f1.y,mu); r8[5]=__fadd_rn(r8[5],__fmul_rn(d,d));
                d=__fsub_rn(f1.z,mu); r8[6]=__fadd_rn(r8[6],__fmul_rn(d,d));
                d=__fsub_rn(f1.w,mu); r8[7]=__fadd_rn(r8[7],__fmul_rn(d,d));
            }
            bss = __fadd_rn(__fadd_rn(__fadd_rn(r8[0],r8[1]), __fadd_rn(r8[2],r8[3])),
                            __fadd_rn(__fadd_rn(r8[4],r8[5]), __fadd_rn(r8[6],r8[7])));
        }
        float v2 = bss;
        v2 = __fadd_rn(v2, __shfl_xor(v2, 1, 64));
        v2 = __fadd_rn(v2, __shfl_xor(v2, 2, 64));
        v2 = __fadd_rn(v2, __shfl_xor(v2, 4, 64));
        const float var0 = __fmul_rn(__shfl(v2, 0, 64), 0.0009765625f);
        const float var4 = __fmul_rn(__shfl(v2, 8, 64), 0.0009765625f);
        rs0 = __fdiv_rn(1.0f, __fsqrt_rn(__fadd_rn(var0, 1e-12f)));
        rs4 = __fdiv_rn(1.0f, __fsqrt_rn(__fadd_rn(var4, 1e-12f)));
    }

    // ---------- Phase C: xn = ((x-mu)*rstd)*gamma + beta, in place ----------
    float4 xn0[2], xn1[2];
    {
        float4 g4[4], b4[4];
#pragma unroll
        for (int q = 0; q < 4; q++) {
            g4[q] = *reinterpret_cast<const float4*>(G  + q*256 + 4*lane);
            b4[q] = *reinterpret_cast<const float4*>(Bt + q*256 + 4*lane);
        }
#pragma unroll
        for (int u = 0; u < 2; u++) {
            const int r = wv + 4*u;
            const float mu = u ? mu4 : mu0;
            const float rstd = u ? rs4 : rs0;
#pragma unroll
            for (int q = 0; q < 4; q++) {
                const int p = q*256 + 4*lane;
                float* ptr = lds + r*RSTR + (p >> 5)*BSTR + (p & 31);
                const float4 x4 = *reinterpret_cast<float4*>(ptr);
                float4 xn;
                xn.x = __fadd_rn(__fmul_rn(__fmul_rn(__fsub_rn(x4.x, mu), rstd), g4[q].x), b4[q].x);
                xn.y = __fadd_rn(__fmul_rn(__fmul_rn(__fsub_rn(x4.y, mu), rstd), g4[q].y), b4[q].y);
                xn.z = __fadd_rn(__fmul_rn(__fmul_rn(__fsub_rn(x4.z, mu), rstd), g4[q].z), b4[q].z);
                xn.w = __fadd_rn(__fmul_rn(__fmul_rn(__fsub_rn(x4.w, mu), rstd), g4[q].w), b4[q].w);
                *reinterpret_cast<float4*>(ptr) = xn;
                if (q == 0) xn0[u] = xn;
                if (q == 1) xn1[u] = xn;
            }
        }
    }
    __syncthreads();

    // ---------- Phase D: 4 BH4 stages, np-einsum order + ascending FWHT ----------
    const int Bm = t >> 3;
    const int j0 = (t & 7) * 4;
#pragma unroll 1
    for (int s = 0; s < 4; s++) {
        float acc[RPB][4];
#pragma unroll
        for (int r = 0; r < RPB; r++)
#pragma unroll
            for (int c = 0; c < 4; c++) acc[r][c] = 0.0f;
        const float* Wb = W + s*32768 + Bm*1024 + j0;
#pragma unroll 2
        for (int iq = 0; iq < 8; iq++) {
            const float4 w0 = *reinterpret_cast<const float4*>(Wb + (iq*4 + 0)*32);
            const float4 w1 = *reinterpret_cast<const float4*>(Wb + (iq*4 + 1)*32);
            const float4 w2 = *reinterpret_cast<const float4*>(Wb + (iq*4 + 2)*32);
            const float4 w3 = *reinterpret_cast<const float4*>(Wb + (iq*4 + 3)*32);
#pragma unroll
            for (int r = 0; r < RPB; r++) {
                const float4 h4 = *reinterpret_cast<const float4*>(lds + r*RSTR + Bm*BSTR + iq*4);
                acc[r][0]=__fadd_rn(acc[r][0],__fmul_rn(h4.x,w0.x));
                acc[r][0]=__fadd_rn(acc[r][0],__fmul_rn(h4.y,w1.x));
                acc[r][0]=__fadd_rn(acc[r][0],__fmul_rn(h4.z,w2.x));
                acc[r][0]=__fadd_rn(acc[r][0],__fmul_rn(h4.w,w3.x));
                acc[r][1]=__fadd_rn(acc[r][1],__fmul_rn(h4.x,w0.y));
                acc[r][1]=__fadd_rn(acc[r][1],__fmul_rn(h4.y,w1.y));
                acc[r][1]=__fadd_rn(acc[r][1],__fmul_rn(h4.z,w2.y));
                acc[r][1]=__fadd_rn(acc[r][1],__fmul_rn(h4.w,w3.y));
                acc[r][2]=__fadd_rn(acc[r][2],__fmul_rn(h4.x,w0.z));
                acc[r][2]=__fadd_rn(acc[r][2],__fmul_rn(h4.y,w1.z));
                acc[r][2]=__fadd_rn(acc[r][2],__fmul_rn(h4.z,w2.z));
                acc[r][2]=__fadd_rn(acc[r][2],__fmul_rn(h4.w,w3.z));
                acc[r][3]=__fadd_rn(acc[r][3],__fmul_rn(h4.x,w0.w));
                acc[r][3]=__fadd_rn(acc[r][3],__fmul_rn(h4.y,w1.w));
                acc[r][3]=__fadd_rn(acc[r][3],__fmul_rn(h4.z,w2.w));
                acc[r][3]=__fadd_rn(acc[r][3],__fmul_rn(h4.w,w3.w));
            }
        }
        // No barrier here: writers below == readers above (group Bm, same wave).
#pragma unroll
        for (int r = 0; r < RPB; r++) {
            const float a = acc[r][0], b = acc[r][1], c = acc[r][2], d = acc[r][3];
            const float s0 = __fadd_rn(a,b), d0 = __fsub_rn(a,b);
            const float s1 = __fadd_rn(c,d), d1 = __fsub_rn(c,d);
            *reinterpret_cast<float4*>(lds + r*RSTR + Bm*BSTR + j0) =
                f4(__fadd_rn(s0,s1), __fadd_rn(d0,d1), __fsub_rn(s0,s1), __fsub_rn(d0,d1));
        }
        __syncthreads();

        {
            const int rr = t >> 5, bb = t & 31;
            float* bp = lds + rr*RSTR + bb*BSTR;
            float4 v[8];
#pragma unroll
            for (int k = 0; k < 8; k++) v[k] = *reinterpret_cast<float4*>(bp + 4*k);
#pragma unroll
            for (int m = 1; m < 8; m <<= 1) {
#pragma unroll
                for (int k = 0; k < 8; k++) if (!(k & m)) {
                    const float4 a = v[k], b = v[k | m];
                    v[k]     = f4(__fadd_rn(a.x,b.x), __fadd_rn(a.y,b.y),
                                  __fadd_rn(a.z,b.z), __fadd_rn(a.w,b.w));
                    v[k | m] = f4(__fsub_rn(a.x,b.x), __fsub_rn(a.y,b.y),
                                  __fsub_rn(a.z,b.z), __fsub_rn(a.w,b.w));
                }
            }
#pragma unroll
            for (int k = 0; k < 8; k++) *reinterpret_cast<float4*>(bp + 4*k) = v[k];
        }
        __syncthreads();

        {
            const int rr = t >> 5, J = t & 31;
            float* bp = lds + rr*RSTR + J;
            float g[32];
#pragma unroll
            for (int k = 0; k < 32; k++) g[k] = bp[k*BSTR];
#pragma unroll
            for (int m = 1; m < 32; m <<= 1) {
#pragma unroll
                for (int k = 0; k < 32; k++) if (!(k & m)) {
                    const float a = g[k], b = g[k | m];
                    g[k] = __fadd_rn(a,b); g[k | m] = __fsub_rn(a,b);
                }
            }
#pragma unroll
            for (int k = 0; k < 32; k++) bp[k*BSTR] = g[k];
        }
        __syncthreads();
    }

    // ---------- Phase E: z = (0.7*h) + (0.3*xn) + bias, p < 320 ----------
    {
        const float c0 = 0.7f, c1 = 0.3f;
#pragma unroll
        for (int u = 0; u < 2; u++) {
            const int r = wv + 4*u;
            {
                const int p = 4*lane;
                const float4 zb = *reinterpret_cast<const float4*>(ZB + p);
                float* zp = lds + r*RSTR + (p >> 5)*BSTR + (p & 31);
                float4 h4 = *reinterpret_cast<float4*>(zp);
                h4.x = __fadd_rn(__fadd_rn(__fmul_rn(c0,h4.x), __fmul_rn(c1,xn0[u].x)), zb.x);
                h4.y = __fadd_rn(__fadd_rn(__fmul_rn(c0,h4.y), __fmul_rn(c1,xn0[u].y)), zb.y);
                h4.z = __fadd_rn(__fadd_rn(__fmul_rn(c0,h4.z), __fmul_rn(c1,xn0[u].z)), zb.z);
                h4.w = __fadd_rn(__fadd_rn(__fmul_rn(c0,h4.w), __fmul_rn(c1,xn0[u].w)), zb.w);
                *reinterpret_cast<float4*>(zp) = h4;
            }
            if (lane < 16) {
                const int p = 256 + 4*lane;
                const float4 zb = *reinterpret_cast<const float4*>(ZB + p);
                float* zp = lds + r*RSTR + (p >> 5)*BSTR + (p & 31);
                float4 h4 = *reinterpret_cast<float4*>(zp);
                h4.x = __fadd_rn(__fadd_rn(__fmul_rn(c0,h4.x), __fmul_rn(c1,xn1[u].x)), zb.x);
                h4.y = __fadd_rn(__fadd_rn(__fmul_rn(c0,h4.y), __fmul_rn(c1,xn1[u].y)), zb.y);
                h4.z = __fadd_rn(__fadd_rn(__fmul_rn(c0,h4.z), __fmul_rn(c1,xn1[u].z)), zb.z);
                h4.w = __fadd_rn(__fadd_rn(__fmul_rn(c0,h4.w), __fmul_rn(c1,xn1[u].w)), zb.w);
                *reinterpret_cast<float4*>(zp) = h4;
            }
        }
    }
    __syncthreads();

    // ---------- Phase F: codes & scores ----------
    {
        const int r = t >> 5, T = t & 31;
        int code = 0; float sc = 1.f;
#pragma unroll
        for (int d = 0; d < CODE_LEN; d++) {
            const int p = T*CODE_LEN + d;
            const float z = lds[r*RSTR + (p >> 5)*BSTR + (p & 31)];
            if (z > 0.f) code |= (1 << d);
            sc *= 1.f / (1.f + expf(-fabsf(z)));
        }
        if constexpr (SPLIT) {
            SC[(size_t)row0 * NUM_TABLE + t] = sc;
            CD[(size_t)row0 * NUM_TABLE + t] = code;
        } else {
            l_sc[t] = sc;
            l_cd[t] = code;
        }
    }

    // ---------- Phase 0' (SPLIT, odd blocks): cast table slice fp32->fp16 ----------
    if constexpr (SPLIT) {
        if (blockIdx.x & 1) do_cast();
    }

    // ---------- Fallback-only: fp32 gather in-kernel (proven R3 path) ----------
    if constexpr (!SPLIT) {
        __syncthreads();
        float4 ob[4];
#pragma unroll
        for (int q = 0; q < 4; q++)
            ob[q] = *reinterpret_cast<const float4*>(OB + q*256 + 4*lane);
#pragma unroll
        for (int u = 0; u < 2; u++) {
            const int r = wv + 4*u;
            float4 o[4];
#pragma unroll
            for (int q = 0; q < 4; q++) o[q] = ob[q];
#pragma unroll 4
            for (int T = 0; T < NUM_TABLE; T++) {
                const float sc  = l_sc[r*NUM_TABLE + T];
                const int code  = l_cd[r*NUM_TABLE + T];
                const float* tbf = TBL + ((size_t)(T*1024 + code)) * 1024;
#pragma unroll
                for (int q = 0; q < 4; q++) {
                    const float4 tv = *reinterpret_cast<const float4*>(tbf + q*256 + 4*lane);
                    o[q].x += sc * tv.x; o[q].y += sc * tv.y;
                    o[q].z += sc * tv.z; o[q].w += sc * tv.w;
                }
            }
            float* orow = OUT + (size_t)(row0 + r) * HIDDEN;
#pragma unroll
            for (int q = 0; q < 4; q++)
                *reinterpret_cast<float4*>(orow + q*256 + 4*lane) = o[q];
        }
    }
}

// ============================================================================
// K2: fp16 gather. One wave per row; lane owns halves [lane*8..+7] and
// [512+lane*8..+7]. 8-table groups; sched_barrier(0) pins the issue/consume
// split (16 loads outstanding). ONLY change vs round 3: launch bounds
// (256,4) -> (256,8). VGPR=64 fits 8 waves/EU exactly (512 VGPR budget);
// grid 2048 = 8 blocks/CU x 256 CUs. Doubles resident waves -> doubles
// in-flight loads for this latency-bound kernel. Plain stores (R4's
// nontemporal f32x4 stores scalarized -> 13x write amplification, 421 MB).
// ============================================================================
__global__ __launch_bounds__(256, 8) void gather_kernel(
    const __half* __restrict__ TBL16,
    const float* __restrict__ SC,
    const int*   __restrict__ CD,
    const float* __restrict__ OB,
    float* __restrict__ OUT)
{
    __shared__ float s_sc[4 * NUM_TABLE];
    __shared__ int   s_cd[4 * NUM_TABLE];
    const int t = threadIdx.x, lane = t & 63, wv = t >> 6;
    const int row0 = blockIdx.x * 4;

    if (t < 128) {
        s_sc[t] = SC[(size_t)row0 * NUM_TABLE + t];
        s_cd[t] = CD[(size_t)row0 * NUM_TABLE + t];
    }
    __syncthreads();

    float4 o[4];
    o[0] = *reinterpret_cast<const float4*>(OB + lane*8);
    o[1] = *reinterpret_cast<const float4*>(OB + lane*8 + 4);
    o[2] = *reinterpret_cast<const float4*>(OB + 512 + lane*8);
    o[3] = *reinterpret_cast<const float4*>(OB + 512 + lane*8 + 4);

#pragma unroll 1
    for (int Tg = 0; Tg < NUM_TABLE; Tg += 8) {
        uint4 va[16];
        float sc[8];
        // ---- issue phase: 16 loads in flight ----
#pragma unroll
        for (int k = 0; k < 8; k++) {
            const int T = Tg + k;
            sc[k] = s_sc[wv*NUM_TABLE + T];
            const int code = s_cd[wv*NUM_TABLE + T];
            const __half* tb = TBL16 + (((size_t)(T*1024 + code)) << 10);
            va[2*k]   = *reinterpret_cast<const uint4*>(tb + lane*8);
            va[2*k+1] = *reinterpret_cast<const uint4*>(tb + 512 + lane*8);
        }
        // pin the split: no load may sink below, no consume may hoist above
        __builtin_amdgcn_sched_barrier(0);
        // ---- consume phase ----
#pragma unroll
        for (int k = 0; k < 8; k++) {
            const __half2* h0 = reinterpret_cast<const __half2*>(&va[2*k]);
            const __half2* h1 = reinterpret_cast<const __half2*>(&va[2*k+1]);
            const float s = sc[k];
            float2 f;
            f = __half22float2(h0[0]); o[0].x += s*f.x; o[0].y += s*f.y;
            f = __half22float2(h0[1]); o[0].z += s*f.x; o[0].w += s*f.y;
            f = __half22float2(h0[2]); o[1].x += s*f.x; o[1].y += s*f.y;
            f = __half22float2(h0[3]); o[1].z += s*f.x; o[1].w += s*f.y;
            f = __half22float2(h1[0]); o[2].x += s*f.x; o[2].y += s*f.y;
            f = __half22float2(h1[1]); o[2].z += s*f.x; o[2].w += s*f.y;
            f = __half22float2(h1[2]); o[3].x += s*f.x; o[3].y += s*f.y;
            f = __half22float2(h1[3]); o[3].z += s*f.x; o[3].w += s*f.y;
        }
    }

    float* orow = OUT + (size_t)(row0 + wv) * HIDDEN;
    *reinterpret_cast<float4*>(orow + lane*8)           = o[0];
    *reinterpret_cast<float4*>(orow + lane*8 + 4)       = o[1];
    *reinterpret_cast<float4*>(orow + 512 + lane*8)     = o[2];
    *reinterpret_cast<float4*>(orow + 512 + lane*8 + 4) = o[3];
}

extern "C" void kernel_launch(void* const* d_in, const int* in_sizes, int n_in,
                              void* d_out, int out_size, void* d_ws, size_t ws_size,
                              hipStream_t stream) {
    const float* X   = (const float*)d_in[0];
    const float* G   = (const float*)d_in[1];
    const float* Bt  = (const float*)d_in[2];
    const float* W   = (const float*)d_in[3];
    const float* ZB  = (const float*)d_in[4];
    const float* TBL = (const float*)d_in[5];
    const float* OB  = (const float*)d_in[6];
    float* OUT = (float*)d_out;

    const int rows = in_sizes[0] / HIDDEN;     // 8192
    const int grid = rows / RPB;               // 1024 blocks

    // ws layout: [tables fp16: 64 MiB][scores: rows*32 f32][codes: rows*32 i32]
    const size_t tbl_bytes = (size_t)TBL_ELEMS * sizeof(__half);
    const size_t sc_bytes  = (size_t)rows * NUM_TABLE * sizeof(float);
    const size_t need = tbl_bytes + 2 * sc_bytes;
    __half* TBL16 = (__half*)d_ws;
    float*  SC    = (float*)((char*)d_ws + tbl_bytes);
    int*    CD    = (int*)((char*)d_ws + tbl_bytes + sc_bytes);

    if (ws_size >= need && grid == 1024) {
        hipLaunchKernelGGL(compute_kernel<true>, dim3(grid), dim3(256), 0, stream,
                           X, G, Bt, W, ZB, TBL, OB, OUT, TBL16, SC, CD);
        hipLaunchKernelGGL(gather_kernel, dim3(rows / 4), dim3(256), 0, stream,
                           TBL16, SC, CD, OB, OUT);
    } else {
        // proven R3 monolithic fp32 path
        hipLaunchKernelGGL(compute_kernel<false>, dim3(grid), dim3(256), 0, stream,
                           X, G, Bt, W, ZB, TBL, OB, OUT, TBL16, SC, CD);
    }
}

// Round 6
// 330.848 us; speedup vs baseline: 1.4035x; 1.3637x over previous
//
#include <hip/hip_runtime.h>
#include <hip/hip_fp16.h>
#include <math.h>

#define HIDDEN 1024
#define CODE_LEN 10
#define NUM_TABLE 32
#define RPB 8            // rows per block (K1)
#define BSTR 36          // padded words per 32-elem block in LDS
#define RSTR (32*BSTR)   // 1152 words per row
#define TBL_ELEMS (32u*1024u*1024u)   // 33,554,432
#define GT 4             // tables per gather group (2*GT loads in flight per buffer)

__device__ __forceinline__ float4 f4(float a, float b, float c, float d) {
    return make_float4(a, b, c, d);
}

// async 16B-per-lane global->LDS. LDS dest is WAVE-UNIFORM base; HW deposits
// lane i at base + i*16. Global addr is per-lane.
__device__ __forceinline__ void gload16(const __half* g, __half* l) {
    __builtin_amdgcn_global_load_lds(
        (const __attribute__((address_space(1))) void*)g,
        (__attribute__((address_space(3))) void*)l,
        16, 0, 0);
}

// ============================================================================
// K1: cast tables fp32->fp16 + bit-exact LN/BH4/codes -> SC/CD in ws.
// EXACT round-3 structure (proven 121.8 us): 2-way block-parity cast stagger,
// scalar __fmul_rn/__fadd_rn einsum, no barrier between einsum and its
// same-wave FWHT4 writeback. CAST=false variant = monolithic fallback.
// ============================================================================
template <bool SPLIT>
__global__ __launch_bounds__(256, 4) void compute_kernel(
    const float* __restrict__ X,   // [rows,1024]
    const float* __restrict__ G,   // [1024] ln_gamma
    const float* __restrict__ Bt,  // [1024] ln_beta
    const float* __restrict__ W,   // [1,4,32,32,32] bh4_weight
    const float* __restrict__ ZB,  // [320] bh4_bias
    const float* __restrict__ TBL, // [32*1024,1024] tables flat (fp32)
    const float* __restrict__ OB,  // [1024] out_bias
    float* __restrict__ OUT,       // [rows,1024]
    __half* __restrict__ TBL16,    // ws: fp16 tables
    float* __restrict__ SC,        // ws: [rows*32] scores
    int*   __restrict__ CD)        // ws: [rows*32] codes
{
    __shared__ float lds[RPB * RSTR];          // 36864 B
    __shared__ float l_sc[RPB * NUM_TABLE];    // only used by !SPLIT path
    __shared__ int   l_cd[RPB * NUM_TABLE];

    const int t    = threadIdx.x;
    const int lane = t & 63;
    const int wv   = t >> 6;
    const int row0 = blockIdx.x * RPB;

    auto do_cast = [&]() {
        const float* src = TBL   + (size_t)blockIdx.x * 32768;
        __half*      dst = TBL16 + (size_t)blockIdx.x * 32768;
#pragma unroll
        for (int k = 0; k < 16; k++) {
            const int idx = (k*256 + t) * 8;
            const float4 a = *reinterpret_cast<const float4*>(src + idx);
            const float4 b = *reinterpret_cast<const float4*>(src + idx + 4);
            union { uint4 u4; __half2 h2[4]; } pk;
            pk.h2[0] = __floats2half2_rn(a.x, a.y);
            pk.h2[1] = __floats2half2_rn(a.z, a.w);
            pk.h2[2] = __floats2half2_rn(b.x, b.y);
            pk.h2[3] = __floats2half2_rn(b.z, b.w);
            *reinterpret_cast<uint4*>(dst + idx) = pk.u4;
        }
    };

    // ---------- Phase 0 (SPLIT, even blocks): cast table slice fp32->fp16 ----------
    if constexpr (SPLIT) {
        if ((blockIdx.x & 1) == 0) do_cast();
    }

    // ---------- Phase A: load raw x into padded LDS ----------
#pragma unroll
    for (int u = 0; u < 2; u++) {
        const int r = wv + 4*u;
        const float* xr = X + (size_t)(row0 + r) * HIDDEN;
#pragma unroll
        for (int q = 0; q < 4; q++) {
            const int p = q*256 + 4*lane;
            const float4 v = *reinterpret_cast<const float4*>(xr + p);
            *reinterpret_cast<float4*>(lds + r*RSTR + (p >> 5)*BSTR + (p & 31)) = v;
        }
    }

    // ---------- Phase B: numpy-pairwise mean/var (bit-exact np.mean order) ----------
    float mu0, mu4, rs0, rs4;
    {
        float bsum = 0.f;
        if (lane < 16) {
            const int row = wv + 4*(lane >> 3);
            const int blk = lane & 7;
            const float* bp = lds + row*RSTR + blk*4*BSTR;
            float r8[8];
            {
                const float4 f0 = *reinterpret_cast<const float4*>(bp);
                const float4 f1 = *reinterpret_cast<const float4*>(bp + 4);
                r8[0]=f0.x; r8[1]=f0.y; r8[2]=f0.z; r8[3]=f0.w;
                r8[4]=f1.x; r8[5]=f1.y; r8[6]=f1.z; r8[7]=f1.w;
            }
#pragma unroll
            for (int m = 1; m < 16; m++) {
                const int p = 8*m;
                const float* qp = bp + (p >> 5)*BSTR + (p & 31);
                const float4 f0 = *reinterpret_cast<const float4*>(qp);
                const float4 f1 = *reinterpret_cast<const float4*>(qp + 4);
                r8[0]=__fadd_rn(r8[0],f0.x); r8[1]=__fadd_rn(r8[1],f0.y);
                r8[2]=__fadd_rn(r8[2],f0.z); r8[3]=__fadd_rn(r8[3],f0.w);
                r8[4]=__fadd_rn(r8[4],f1.x); r8[5]=__fadd_rn(r8[5],f1.y);
                r8[6]=__fadd_rn(r8[6],f1.z); r8[7]=__fadd_rn(r8[7],f1.w);
            }
            bsum = __fadd_rn(__fadd_rn(__fadd_rn(r8[0],r8[1]), __fadd_rn(r8[2],r8[3])),
                             __fadd_rn(__fadd_rn(r8[4],r8[5]), __fadd_rn(r8[6],r8[7])));
        }
        float v = bsum;
        v = __fadd_rn(v, __shfl_xor(v, 1, 64));
        v = __fadd_rn(v, __shfl_xor(v, 2, 64));
        v = __fadd_rn(v, __shfl_xor(v, 4, 64));
        mu0 = __fmul_rn(__shfl(v, 0, 64), 0.0009765625f);
        mu4 = __fmul_rn(__shfl(v, 8, 64), 0.0009765625f);

        float bss = 0.f;
        if (lane < 16) {
            const int row = wv + 4*(lane >> 3);
            const float mu = (lane & 8) ? mu4 : mu0;
            const int blk = lane & 7;
            const float* bp = lds + row*RSTR + blk*4*BSTR;
            float r8[8];
            {
                const float4 f0 = *reinterpret_cast<const float4*>(bp);
                const float4 f1 = *reinterpret_cast<const float4*>(bp + 4);
                float d;
                d=__fsub_rn(f0.x,mu); r8[0]=__fmul_rn(d,d);
                d=__fsub_rn(f0.y,mu); r8[1]=__fmul_rn(d,d);
                d=__fsub_rn(f0.z,mu); r8[2]=__fmul_rn(d,d);
                d=__fsub_rn(f0.w,mu); r8[3]=__fmul_rn(d,d);
                d=__fsub_rn(f1.x,mu); r8[4]=__fmul_rn(d,d);
                d=__fsub_rn(f1.y,mu); r8[5]=__fmul_rn(d,d);
                d=__fsub_rn(f1.z,mu); r8[6]=__fmul_rn(d,d);
                d=__fsub_rn(f1.w,mu); r8[7]=__fmul_rn(d,d);
            }
#pragma unroll
            for (int m = 1; m < 16; m++) {
                const int p = 8*m;
                const float* qp = bp + (p >> 5)*BSTR + (p & 31);
                const float4 f0 = *reinterpret_cast<const float4*>(qp);
                const float4 f1 = *reinterpret_cast<const float4*>(qp + 4);
                float d;
                d=__fsub_rn(f0.x,mu); r8[0]=__fadd_rn(r8[0],__fmul_rn(d,d));
                d=__fsub_rn(f0.y,mu); r8[1]=__fadd_rn(r8[1],__fmul_rn(d,d));
                d=__fsub_rn(f0.z,mu); r8[2]=__fadd_rn(r8[2],__fmul_rn(d,d));
                d=__fsub_rn(f0.w,mu); r8[3]=__fadd_rn(r8[3],__fmul_rn(d,d));
                d=__fsub_rn(f1.x,mu); r8[4]=__fadd_rn(r8[4],__fmul_rn(d,d));
                d=__fsub_rn(f1.y,mu); r8[5]=__fadd_rn(r8[5],__fmul_rn(d,d));
                d=__fsub_rn(f1.z,mu); r8[6]=__fadd_rn(r8[6],__fmul_rn(d,d));
                d=__fsub_rn(f1.w,mu); r8[7]=__fadd_rn(r8[7],__fmul_rn(d,d));
            }
            bss = __fadd_rn(__fadd_rn(__fadd_rn(r8[0],r8[1]), __fadd_rn(r8[2],r8[3])),
                            __fadd_rn(__fadd_rn(r8[4],r8[5]), __fadd_rn(r8[6],r8[7])));
        }
        float v2 = bss;
        v2 = __fadd_rn(v2, __shfl_xor(v2, 1, 64));
        v2 = __fadd_rn(v2, __shfl_xor(v2, 2, 64));
        v2 = __fadd_rn(v2, __shfl_xor(v2, 4, 64));
        const float var0 = __fmul_rn(__shfl(v2, 0, 64), 0.0009765625f);
        const float var4 = __fmul_rn(__shfl(v2, 8, 64), 0.0009765625f);
        rs0 = __fdiv_rn(1.0f, __fsqrt_rn(__fadd_rn(var0, 1e-12f)));
        rs4 = __fdiv_rn(1.0f, __fsqrt_rn(__fadd_rn(var4, 1e-12f)));
    }

    // ---------- Phase C: xn = ((x-mu)*rstd)*gamma + beta, in place ----------
    float4 xn0[2], xn1[2];
    {
        float4 g4[4], b4[4];
#pragma unroll
        for (int q = 0; q < 4; q++) {
            g4[q] = *reinterpret_cast<const float4*>(G  + q*256 + 4*lane);
            b4[q] = *reinterpret_cast<const float4*>(Bt + q*256 + 4*lane);
        }
#pragma unroll
        for (int u = 0; u < 2; u++) {
            const int r = wv + 4*u;
            const float mu = u ? mu4 : mu0;
            const float rstd = u ? rs4 : rs0;
#pragma unroll
            for (int q = 0; q < 4; q++) {
                const int p = q*256 + 4*lane;
                float* ptr = lds + r*RSTR + (p >> 5)*BSTR + (p & 31);
                const float4 x4 = *reinterpret_cast<float4*>(ptr);
                float4 xn;
                xn.x = __fadd_rn(__fmul_rn(__fmul_rn(__fsub_rn(x4.x, mu), rstd), g4[q].x), b4[q].x);
                xn.y = __fadd_rn(__fmul_rn(__fmul_rn(__fsub_rn(x4.y, mu), rstd), g4[q].y), b4[q].y);
                xn.z = __fadd_rn(__fmul_rn(__fmul_rn(__fsub_rn(x4.z, mu), rstd), g4[q].z), b4[q].z);
                xn.w = __fadd_rn(__fmul_rn(__fmul_rn(__fsub_rn(x4.w, mu), rstd), g4[q].w), b4[q].w);
                *reinterpret_cast<float4*>(ptr) = xn;
                if (q == 0) xn0[u] = xn;
                if (q == 1) xn1[u] = xn;
            }
        }
    }
    __syncthreads();

    // ---------- Phase D: 4 BH4 stages, np-einsum order + ascending FWHT ----------
    const int Bm = t >> 3;
    const int j0 = (t & 7) * 4;
#pragma unroll 1
    for (int s = 0; s < 4; s++) {
        float acc[RPB][4];
#pragma unroll
        for (int r = 0; r < RPB; r++)
#pragma unroll
            for (int c = 0; c < 4; c++) acc[r][c] = 0.0f;
        const float* Wb = W + s*32768 + Bm*1024 + j0;
#pragma unroll 2
        for (int iq = 0; iq < 8; iq++) {
            const float4 w0 = *reinterpret_cast<const float4*>(Wb + (iq*4 + 0)*32);
            const float4 w1 = *reinterpret_cast<const float4*>(Wb + (iq*4 + 1)*32);
            const float4 w2 = *reinterpret_cast<const float4*>(Wb + (iq*4 + 2)*32);
            const float4 w3 = *reinterpret_cast<const float4*>(Wb + (iq*4 + 3)*32);
#pragma unroll
            for (int r = 0; r < RPB; r++) {
                const float4 h4 = *reinterpret_cast<const float4*>(lds + r*RSTR + Bm*BSTR + iq*4);
                acc[r][0]=__fadd_rn(acc[r][0],__fmul_rn(h4.x,w0.x));
                acc[r][0]=__fadd_rn(acc[r][0],__fmul_rn(h4.y,w1.x));
                acc[r][0]=__fadd_rn(acc[r][0],__fmul_rn(h4.z,w2.x));
                acc[r][0]=__fadd_rn(acc[r][0],__fmul_rn(h4.w,w3.x));
                acc[r][1]=__fadd_rn(acc[r][1],__fmul_rn(h4.x,w0.y));
                acc[r][1]=__fadd_rn(acc[r][1],__fmul_rn(h4.y,w1.y));
                acc[r][1]=__fadd_rn(acc[r][1],__fmul_rn(h4.z,w2.y));
                acc[r][1]=__fadd_rn(acc[r][1],__fmul_rn(h4.w,w3.y));
                acc[r][2]=__fadd_rn(acc[r][2],__fmul_rn(h4.x,w0.z));
                acc[r][2]=__fadd_rn(acc[r][2],__fmul_rn(h4.y,w1.z));
                acc[r][2]=__fadd_rn(acc[r][2],__fmul_rn(h4.z,w2.z));
                acc[r][2]=__fadd_rn(acc[r][2],__fmul_rn(h4.w,w3.z));
                acc[r][3]=__fadd_rn(acc[r][3],__fmul_rn(h4.x,w0.w));
                acc[r][3]=__fadd_rn(acc[r][3],__fmul_rn(h4.y,w1.w));
                acc[r][3]=__fadd_rn(acc[r][3],__fmul_rn(h4.z,w2.w));
                acc[r][3]=__fadd_rn(acc[r][3],__fmul_rn(h4.w,w3.w));
            }
        }
        // No barrier here: writers below == readers above (group Bm, same wave).
#pragma unroll
        for (int r = 0; r < RPB; r++) {
            const float a = acc[r][0], b = acc[r][1], c = acc[r][2], d = acc[r][3];
            const float s0 = __fadd_rn(a,b), d0 = __fsub_rn(a,b);
            const float s1 = __fadd_rn(c,d), d1 = __fsub_rn(c,d);
            *reinterpret_cast<float4*>(lds + r*RSTR + Bm*BSTR + j0) =
                f4(__fadd_rn(s0,s1), __fadd_rn(d0,d1), __fsub_rn(s0,s1), __fsub_rn(d0,d1));
        }
        __syncthreads();

        {
            const int rr = t >> 5, bb = t & 31;
            float* bp = lds + rr*RSTR + bb*BSTR;
            float4 v[8];
#pragma unroll
            for (int k = 0; k < 8; k++) v[k] = *reinterpret_cast<float4*>(bp + 4*k);
#pragma unroll
            for (int m = 1; m < 8; m <<= 1) {
#pragma unroll
                for (int k = 0; k < 8; k++) if (!(k & m)) {
                    const float4 a = v[k], b = v[k | m];
                    v[k]     = f4(__fadd_rn(a.x,b.x), __fadd_rn(a.y,b.y),
                                  __fadd_rn(a.z,b.z), __fadd_rn(a.w,b.w));
                    v[k | m] = f4(__fsub_rn(a.x,b.x), __fsub_rn(a.y,b.y),
                                  __fsub_rn(a.z,b.z), __fsub_rn(a.w,b.w));
                }
            }
#pragma unroll
            for (int k = 0; k < 8; k++) *reinterpret_cast<float4*>(bp + 4*k) = v[k];
        }
        __syncthreads();

        {
            const int rr = t >> 5, J = t & 31;
            float* bp = lds + rr*RSTR + J;
            float g[32];
#pragma unroll
            for (int k = 0; k < 32; k++) g[k] = bp[k*BSTR];
#pragma unroll
            for (int m = 1; m < 32; m <<= 1) {
#pragma unroll
                for (int k = 0; k < 32; k++) if (!(k & m)) {
                    const float a = g[k], b = g[k | m];
                    g[k] = __fadd_rn(a,b); g[k | m] = __fsub_rn(a,b);
                }
            }
#pragma unroll
            for (int k = 0; k < 32; k++) bp[k*BSTR] = g[k];
        }
        __syncthreads();
    }

    // ---------- Phase E: z = (0.7*h) + (0.3*xn) + bias, p < 320 ----------
    {
        const float c0 = 0.7f, c1 = 0.3f;
#pragma unroll
        for (int u = 0; u < 2; u++) {
            const int r = wv + 4*u;
            {
                const int p = 4*lane;
                const float4 zb = *reinterpret_cast<const float4*>(ZB + p);
                float* zp = lds + r*RSTR + (p >> 5)*BSTR + (p & 31);
                float4 h4 = *reinterpret_cast<float4*>(zp);
                h4.x = __fadd_rn(__fadd_rn(__fmul_rn(c0,h4.x), __fmul_rn(c1,xn0[u].x)), zb.x);
                h4.y = __fadd_rn(__fadd_rn(__fmul_rn(c0,h4.y), __fmul_rn(c1,xn0[u].y)), zb.y);
                h4.z = __fadd_rn(__fadd_rn(__fmul_rn(c0,h4.z), __fmul_rn(c1,xn0[u].z)), zb.z);
                h4.w = __fadd_rn(__fadd_rn(__fmul_rn(c0,h4.w), __fmul_rn(c1,xn0[u].w)), zb.w);
                *reinterpret_cast<float4*>(zp) = h4;
            }
            if (lane < 16) {
                const int p = 256 + 4*lane;
                const float4 zb = *reinterpret_cast<const float4*>(ZB + p);
                float* zp = lds + r*RSTR + (p >> 5)*BSTR + (p & 31);
                float4 h4 = *reinterpret_cast<float4*>(zp);
                h4.x = __fadd_rn(__fadd_rn(__fmul_rn(c0,h4.x), __fmul_rn(c1,xn1[u].x)), zb.x);
                h4.y = __fadd_rn(__fadd_rn(__fmul_rn(c0,h4.y), __fmul_rn(c1,xn1[u].y)), zb.y);
                h4.z = __fadd_rn(__fadd_rn(__fmul_rn(c0,h4.z), __fmul_rn(c1,xn1[u].z)), zb.z);
                h4.w = __fadd_rn(__fadd_rn(__fmul_rn(c0,h4.w), __fmul_rn(c1,xn1[u].w)), zb.w);
                *reinterpret_cast<float4*>(zp) = h4;
            }
        }
    }
    __syncthreads();

    // ---------- Phase F: codes & scores ----------
    {
        const int r = t >> 5, T = t & 31;
        int code = 0; float sc = 1.f;
#pragma unroll
        for (int d = 0; d < CODE_LEN; d++) {
            const int p = T*CODE_LEN + d;
            const float z = lds[r*RSTR + (p >> 5)*BSTR + (p & 31)];
            if (z > 0.f) code |= (1 << d);
            sc *= 1.f / (1.f + expf(-fabsf(z)));
        }
        if constexpr (SPLIT) {
            SC[(size_t)row0 * NUM_TABLE + t] = sc;
            CD[(size_t)row0 * NUM_TABLE + t] = code;
        } else {
            l_sc[t] = sc;
            l_cd[t] = code;
        }
    }

    // ---------- Phase 0' (SPLIT, odd blocks): cast table slice fp32->fp16 ----------
    if constexpr (SPLIT) {
        if (blockIdx.x & 1) do_cast();
    }

    // ---------- Fallback-only: fp32 gather in-kernel (proven R3 path) ----------
    if constexpr (!SPLIT) {
        __syncthreads();
        float4 ob[4];
#pragma unroll
        for (int q = 0; q < 4; q++)
            ob[q] = *reinterpret_cast<const float4*>(OB + q*256 + 4*lane);
#pragma unroll
        for (int u = 0; u < 2; u++) {
            const int r = wv + 4*u;
            float4 o[4];
#pragma unroll
            for (int q = 0; q < 4; q++) o[q] = ob[q];
#pragma unroll 4
            for (int T = 0; T < NUM_TABLE; T++) {
                const float sc  = l_sc[r*NUM_TABLE + T];
                const int code  = l_cd[r*NUM_TABLE + T];
                const float* tbf = TBL + ((size_t)(T*1024 + code)) * 1024;
#pragma unroll
                for (int q = 0; q < 4; q++) {
                    const float4 tv = *reinterpret_cast<const float4*>(tbf + q*256 + 4*lane);
                    o[q].x += sc * tv.x; o[q].y += sc * tv.y;
                    o[q].z += sc * tv.z; o[q].w += sc * tv.w;
                }
            }
            float* orow = OUT + (size_t)(row0 + r) * HIDDEN;
#pragma unroll
            for (int q = 0; q < 4; q++)
                *reinterpret_cast<float4*>(orow + q*256 + 4*lane) = o[q];
        }
    }
}

// ============================================================================
// K2: fp16 gather, LDS-staged via global_load_lds. One wave per row.
// In-flight bytes no longer live in VGPRs: each wave keeps up to 16 async
// 1KB loads outstanding (vmcnt-tracked), double-buffered in a 64 KiB stage.
// Counted waits (vmcnt(8), never 0 mid-loop) per the T3/T4 pattern;
// lgkmcnt(0) before each buffer overwrite. Scores/codes in registers+shfl.
// Consume arithmetic token-identical to R3 -> bit-identical output.
// ============================================================================
__global__ __launch_bounds__(256, 2) void gather_kernel(
    const __half* __restrict__ TBL16,
    const float* __restrict__ SC,
    const int*   __restrict__ CD,
    const float* __restrict__ OB,
    float* __restrict__ OUT)
{
    __shared__ __half stage[4][2][GT*1024];   // 4 waves x 2 bufs x 8KB = 64 KiB
    const int t = threadIdx.x, lane = t & 63, wv = t >> 6;
    const int row = blockIdx.x * 4 + wv;

    // lane k<32 holds table k's score/code for this wave's row
    float my_sc = 0.f; int my_cd = 0;
    if (lane < 32) {
        my_sc = SC[(size_t)row * NUM_TABLE + lane];
        my_cd = CD[(size_t)row * NUM_TABLE + lane];
    }

    float4 o[4];
    o[0] = *reinterpret_cast<const float4*>(OB + lane*8);
    o[1] = *reinterpret_cast<const float4*>(OB + lane*8 + 4);
    o[2] = *reinterpret_cast<const float4*>(OB + 512 + lane*8);
    o[3] = *reinterpret_cast<const float4*>(OB + 512 + lane*8 + 4);

    __half* st0 = &stage[wv][0][0];
    __half* st1 = &stage[wv][1][0];

    auto issue = [&](int g, __half* buf) {
#pragma unroll
        for (int k = 0; k < GT; ++k) {
            const int T = g*GT + k;
            const int code = __shfl(my_cd, T, 64);
            const __half* tb = TBL16 + (((size_t)(T*1024 + code)) << 10);
            // wave-uniform LDS base; HW deposits lane i at base + i*16B
            gload16(tb + lane*8,       buf + k*1024);
            gload16(tb + 512 + lane*8, buf + k*1024 + 512);
        }
    };

    issue(0, st0);   // prologue: group 0 in flight (8 loads)

#pragma unroll
    for (int g = 0; g < NUM_TABLE/GT; ++g) {
        __half* cur = (g & 1) ? st1 : st0;
        __half* nxt = (g & 1) ? st0 : st1;
        if (g < NUM_TABLE/GT - 1) {
            issue(g+1, nxt);                              // 16 loads in flight
            asm volatile("s_waitcnt vmcnt(8)" ::: "memory");  // group g landed
        } else {
            asm volatile("s_waitcnt vmcnt(0)" ::: "memory");  // drain last
        }
        __builtin_amdgcn_sched_barrier(0);
#pragma unroll
        for (int k = 0; k < GT; ++k) {
            const int T = g*GT + k;
            const float s = __shfl(my_sc, T, 64);
            const float4 lo4 = *reinterpret_cast<const float4*>(cur + k*1024 + lane*8);
            const float4 hi4 = *reinterpret_cast<const float4*>(cur + k*1024 + 512 + lane*8);
            const __half2* h0 = reinterpret_cast<const __half2*>(&lo4);
            const __half2* h1 = reinterpret_cast<const __half2*>(&hi4);
            float2 f;
            f = __half22float2(h0[0]); o[0].x += s*f.x; o[0].y += s*f.y;
            f = __half22float2(h0[1]); o[0].z += s*f.x; o[0].w += s*f.y;
            f = __half22float2(h0[2]); o[1].x += s*f.x; o[1].y += s*f.y;
            f = __half22float2(h0[3]); o[1].z += s*f.x; o[1].w += s*f.y;
            f = __half22float2(h1[0]); o[2].x += s*f.x; o[2].y += s*f.y;
            f = __half22float2(h1[1]); o[2].z += s*f.x; o[2].w += s*f.y;
            f = __half22float2(h1[2]); o[3].x += s*f.x; o[3].y += s*f.y;
            f = __half22float2(h1[3]); o[3].z += s*f.x; o[3].w += s*f.y;
        }
        // ds_reads must retire before next issue overwrites this buffer
        asm volatile("s_waitcnt lgkmcnt(0)" ::: "memory");
        __builtin_amdgcn_sched_barrier(0);
    }

    float* orow = OUT + (size_t)row * HIDDEN;
    *reinterpret_cast<float4*>(orow + lane*8)           = o[0];
    *reinterpret_cast<float4*>(orow + lane*8 + 4)       = o[1];
    *reinterpret_cast<float4*>(orow + 512 + lane*8)     = o[2];
    *reinterpret_cast<float4*>(orow + 512 + lane*8 + 4) = o[3];
}

extern "C" void kernel_launch(void* const* d_in, const int* in_sizes, int n_in,
                              void* d_out, int out_size, void* d_ws, size_t ws_size,
                              hipStream_t stream) {
    const float* X   = (const float*)d_in[0];
    const float* G   = (const float*)d_in[1];
    const float* Bt  = (const float*)d_in[2];
    const float* W   = (const float*)d_in[3];
    const float* ZB  = (const float*)d_in[4];
    const float* TBL = (const float*)d_in[5];
    const float* OB  = (const float*)d_in[6];
    float* OUT = (float*)d_out;

    const int rows = in_sizes[0] / HIDDEN;     // 8192
    const int grid = rows / RPB;               // 1024 blocks

    // ws layout: [tables fp16: 64 MiB][scores: rows*32 f32][codes: rows*32 i32]
    const size_t tbl_bytes = (size_t)TBL_ELEMS * sizeof(__half);
    const size_t sc_bytes  = (size_t)rows * NUM_TABLE * sizeof(float);
    const size_t need = tbl_bytes + 2 * sc_bytes;
    __half* TBL16 = (__half*)d_ws;
    float*  SC    = (float*)((char*)d_ws + tbl_bytes);
    int*    CD    = (int*)((char*)d_ws + tbl_bytes + sc_bytes);

    if (ws_size >= need && grid == 1024) {
        hipLaunchKernelGGL(compute_kernel<true>, dim3(grid), dim3(256), 0, stream,
                           X, G, Bt, W, ZB, TBL, OB, OUT, TBL16, SC, CD);
        hipLaunchKernelGGL(gather_kernel, dim3(rows / 4), dim3(256), 0, stream,
                           TBL16, SC, CD, OB, OUT);
    } else {
        // proven R3 monolithic fp32 path
        hipLaunchKernelGGL(compute_kernel<false>, dim3(grid), dim3(256), 0, stream,
                           X, G, Bt, W, ZB, TBL, OB, OUT, TBL16, SC, CD);
    }
}